// Round 9
// baseline (200.587 us; speedup 1.0000x reference)
//
#include <hip/hip_runtime.h>

typedef _Float16 half_t;
typedef _Float16 half8 __attribute__((ext_vector_type(8)));
typedef _Float16 half4_t __attribute__((ext_vector_type(4)));
typedef float floatx4 __attribute__((ext_vector_type(4)));
typedef float floatx16 __attribute__((ext_vector_type(16)));

#define B_SZ 2
#define SEQ 2048
#define DIM_ 1024
#define NH 16
#define DH 64
#define ROWS (B_SZ * SEQ)   // 4096

// async global->LDS, 16B per lane; LDS dest MUST be wave-uniform base (+lane*16)
__device__ __forceinline__ void gl2lds16(const void* g, void* l) {
  __builtin_amdgcn_global_load_lds((const __attribute__((address_space(1))) unsigned int*)g,
                                   (__attribute__((address_space(3))) unsigned int*)l, 16, 0, 0);
}

// one kernel converts x, w_qkv, w_proj (contiguous in ws) fp32->fp16
__global__ __launch_bounds__(256) void convert_all(const float4* __restrict__ x,
                                                   const float4* __restrict__ wq,
                                                   const float4* __restrict__ wp,
                                                   half4_t* __restrict__ dst,
                                                   int nx, int nq, int np) {
  int i = blockIdx.x * blockDim.x + threadIdx.x;
  float4 v;
  if (i < nx) v = x[i];
  else if (i < nx + nq) v = wq[i - nx];
  else if (i < nx + nq + np) v = wp[i - nx - nq];
  else return;
  half4_t h;
  h.x = (half_t)v.x; h.y = (half_t)v.y; h.z = (half_t)v.z; h.w = (half_t)v.w;
  dst[i] = h;
}

// C = A[4096][1024] @ Bt[N][1024]^T. 32x32x16 MFMA, BK=32, 128xBN tile, 4 waves.
// Double-buffered LDS, single barrier per K-iter. Pair-interleaved LDS layout:
// seg s -> row=((s>>3)<<1)|(s&1), c=(s>>1)&3 => row-pair stride 128B (bank-neutral),
// chunk swizzle c^((row>>2)&3) => fragment reads max 2-way bank aliasing (free).
// MODE 0 (BN=128): qkv epilogue. MODE 1 (BN=64): proj fp32 out.
template <int MODE, int BN>
__global__ __launch_bounds__(256, 3) void gemm32(const half_t* __restrict__ A,
                                                 const half_t* __restrict__ Bt,
                                                 half_t* __restrict__ q16,
                                                 half_t* __restrict__ k16,
                                                 half_t* __restrict__ vT16,
                                                 float* __restrict__ outp) {
  constexpr int K = 1024;
  constexpr int BK = 32;
  constexpr int NT = BN / 64;  // 32x32 n-tiles per wave
  __shared__ __align__(16) half_t a_lds[2][128 * BK];
  __shared__ __align__(16) half_t b_lds[2][BN * BK];
  const int t = threadIdx.x;
  const int wave = t >> 6, lane = t & 63;
  const int l31 = lane & 31, hw = lane >> 5;
  const int wm = wave >> 1, wn = wave & 1;
  const int row0 = blockIdx.y * 128, col0 = blockIdx.x * BN;

  floatx16 acc[2][NT];
#pragma unroll
  for (int i = 0; i < 2; ++i)
#pragma unroll
    for (int j = 0; j < NT; ++j)
#pragma unroll
      for (int r = 0; r < 16; ++r) acc[i][j][r] = 0.f;

  auto stage = [&](int buf, int k0) {
    // A: 128 rows x 4 chunks = 512 segs, 2/thread
#pragma unroll
    for (int hi = 0; hi < 2; ++hi) {
      int s = t + hi * 256;
      int row = ((s >> 3) << 1) | (s & 1);
      int c = (s >> 1) & 3;
      int sc = c ^ ((row >> 2) & 3);
      gl2lds16(A + (size_t)(row0 + row) * K + (k0 + sc * 8),
               &a_lds[buf][(wave * 64 + hi * 256) * 8]);
    }
    // B: BN rows x 4 chunks = BN*4 segs -> BN/64 iterations of 256
#pragma unroll
    for (int hi = 0; hi < BN / 64; ++hi) {
      int s = t + hi * 256;
      int row = ((s >> 3) << 1) | (s & 1);
      int c = (s >> 1) & 3;
      int sc = c ^ ((row >> 2) & 3);
      gl2lds16(Bt + (size_t)(col0 + row) * K + (k0 + sc * 8),
               &b_lds[buf][(wave * 64 + hi * 256) * 8]);
    }
  };

  stage(0, 0);
  int cur = 0;
  for (int k0 = 0; k0 < K; k0 += BK) {
    __syncthreads();  // publishes buf[cur], protects buf[cur^1]
    if (k0 + BK < K) stage(cur ^ 1, k0 + BK);

#pragma unroll
    for (int kf = 0; kf < 2; ++kf) {
      half8 af[2], bf[NT];
#pragma unroll
      for (int mt = 0; mt < 2; ++mt) {
        int row = wm * 64 + mt * 32 + l31;
        int c_lds = ((kf << 1) | hw) ^ ((row >> 2) & 3);
        af[mt] = *(const half8*)(&a_lds[cur][(row >> 1) * 64 + c_lds * 16 + (row & 1) * 8]);
      }
#pragma unroll
      for (int nt = 0; nt < NT; ++nt) {
        int row = wn * (BN / 2) + nt * 32 + l31;
        int c_lds = ((kf << 1) | hw) ^ ((row >> 2) & 3);
        bf[nt] = *(const half8*)(&b_lds[cur][(row >> 1) * 64 + c_lds * 16 + (row & 1) * 8]);
      }
#pragma unroll
      for (int mt = 0; mt < 2; ++mt)
#pragma unroll
        for (int nt = 0; nt < NT; ++nt)
          acc[mt][nt] = __builtin_amdgcn_mfma_f32_32x32x16_f16(af[mt], bf[nt], acc[mt][nt], 0, 0, 0);
    }
    cur ^= 1;
  }

  // C/D 32x32 mapping: col = lane&31, row = (r&3) + 8*(r>>2) + 4*(lane>>5)
  if (MODE == 0) {
    const int which = col0 >> 10;
#pragma unroll
    for (int mt = 0; mt < 2; ++mt)
#pragma unroll
      for (int nt = 0; nt < NT; ++nt) {
        int growb = row0 + wm * 64 + mt * 32;
        int gcol = col0 + wn * (BN / 2) + nt * 32 + l31;
        int hc = gcol & 1023, h = hc >> 6, d = hc & 63;
        if (which == 2) {
#pragma unroll
          for (int rq = 0; rq < 4; ++rq) {
            int grow = growb + 8 * rq + 4 * hw;
            int b = grow >> 11, n0 = grow & 2047;
            int bh = b * NH + h;
            half4_t h4;
            h4.x = (half_t)acc[mt][nt][rq * 4 + 0];
            h4.y = (half_t)acc[mt][nt][rq * 4 + 1];
            h4.z = (half_t)acc[mt][nt][rq * 4 + 2];
            h4.w = (half_t)acc[mt][nt][rq * 4 + 3];
            *(half4_t*)(vT16 + ((size_t)bh * DH + d) * SEQ + n0) = h4;
          }
        } else {
#pragma unroll
          for (int r = 0; r < 16; ++r) {
            int grow = growb + (r & 3) + 8 * (r >> 2) + 4 * hw;
            int b = grow >> 11, n = grow & 2047;
            int bh = b * NH + h;
            float v = acc[mt][nt][r];
            if (which == 0)
              // fold SCALE * log2(e): attn uses exp2
              q16[((size_t)bh * SEQ + n) * DH + d] = (half_t)(v * 0.18033688011112042f);
            else
              k16[((size_t)bh * SEQ + n) * DH + d] = (half_t)v;
          }
        }
      }
  } else {
#pragma unroll
    for (int mt = 0; mt < 2; ++mt)
#pragma unroll
      for (int nt = 0; nt < NT; ++nt) {
        int growb = row0 + wm * 64 + mt * 32;
        int gcol = col0 + wn * (BN / 2) + nt * 32 + l31;
#pragma unroll
        for (int r = 0; r < 16; ++r) {
          int grow = growb + (r & 3) + 8 * (r >> 2) + 4 * hw;
          outp[(size_t)grow * DIM_ + gcol] = acc[mt][nt][r];
        }
      }
  }
}

// Flash attention pass 1, j-split 2-way. Block = (bh, 128 q-rows, j-half).
// 4 waves x 32 q-rows (2 m-tiles), S^T trick (P^T regs feed K=16 PV MFMA).
// p = exp2(S') with log2e pre-folded into q. Row-sums via O_extra = P @ ones
// MFMA (register-aligned with o; no shuffles). launch_bounds(256,4).
__global__ __launch_bounds__(256, 4) void attn_p1(const half_t* __restrict__ q16,
                                                  const half_t* __restrict__ k16,
                                                  const half_t* __restrict__ vT16,
                                                  half_t* __restrict__ opart,
                                                  float* __restrict__ psums) {
  __shared__ __align__(16) half_t k_lds[2][64 * 64];  // [j][d]
  __shared__ __align__(16) half_t v_lds[2][64 * 64];  // vT: [d][j]

  const int t = threadIdx.x;
  const int wave = t >> 6, lane = t & 63;
  const int l15 = lane & 15, quad = lane >> 4;
  const int blk = blockIdx.x;
  const int js = blk & 1, qt = (blk >> 1) & 15, bh = blk >> 5;
  const half_t* qp = q16 + (size_t)bh * SEQ * DH;
  const half_t* kp = k16 + (size_t)bh * SEQ * DH;
  const half_t* vp = vT16 + (size_t)bh * DH * SEQ;
  const int q0w = qt * 128 + wave * 32;
  const int jbase = js * 1024;

  // staging offsets: 512 segs of 16B (64 rows x 8 chunks), chunk XOR row&7
  const int s0 = t, s1 = t + 256;
  const int r0_ = s0 >> 3, c0_ = (s0 & 7) ^ (r0_ & 7);
  const int r1_ = s1 >> 3, c1_ = (s1 & 7) ^ (r1_ & 7);

  // Q fragments, B-operand layout: lane l15 = q-row, k = kf*32 + quad*8 + i
  half8 qf[2][2];
#pragma unroll
  for (int mi = 0; mi < 2; ++mi)
#pragma unroll
    for (int kf = 0; kf < 2; ++kf)
      qf[mi][kf] = *(const half8*)(qp + (size_t)(q0w + mi * 16 + l15) * DH + kf * 32 + quad * 8);

  const floatx4 z4 = {0.f, 0.f, 0.f, 0.f};
  floatx4 o[2][4];   // [mi][d-tile], C/D: row=q(quad*4+r), col=d(l15)
  floatx4 osum[2];   // row-sums via P @ ones, same C/D layout (col-replicated)
#pragma unroll
  for (int mi = 0; mi < 2; ++mi) {
    osum[mi] = z4;
#pragma unroll
    for (int i = 0; i < 4; ++i) o[mi][i] = z4;
  }

  gl2lds16(kp + (size_t)(jbase + r0_) * DH + c0_ * 8, &k_lds[0][(wave * 64) * 8]);
  gl2lds16(vp + (size_t)r0_ * SEQ + jbase + c0_ * 8, &v_lds[0][(wave * 64) * 8]);
  gl2lds16(kp + (size_t)(jbase + r1_) * DH + c1_ * 8, &k_lds[0][(wave * 64 + 256) * 8]);
  gl2lds16(vp + (size_t)r1_ * SEQ + jbase + c1_ * 8, &v_lds[0][(wave * 64 + 256) * 8]);

  const half_t one_h = (half_t)1.f;
  const half4_t vone = {one_h, one_h, one_h, one_h};

  int cur = 0;
  for (int jt = 0; jt < 16; ++jt) {
    __syncthreads();  // publishes buf[cur], protects buf[cur^1]

    if (jt + 1 < 16) {
      const int j0 = jbase + (jt + 1) * 64, nb = cur ^ 1;
      gl2lds16(kp + (size_t)(j0 + r0_) * DH + c0_ * 8, &k_lds[nb][(wave * 64) * 8]);
      gl2lds16(vp + (size_t)r0_ * SEQ + j0 + c0_ * 8, &v_lds[nb][(wave * 64) * 8]);
      gl2lds16(kp + (size_t)(j0 + r1_) * DH + c1_ * 8, &k_lds[nb][(wave * 64 + 256) * 8]);
      gl2lds16(vp + (size_t)r1_ * SEQ + j0 + c1_ * 8, &v_lds[nb][(wave * 64 + 256) * 8]);
    }

    const half_t* kl = k_lds[cur];
    const half_t* vl = v_lds[cur];

    // Per nt: S^T MFMAs -> exp2 -> packed P fragment (st lives only 8 regs)
    half4_t pf[2][4];
#pragma unroll
    for (int nt = 0; nt < 4; ++nt) {
      int row = nt * 16 + l15;  // j-row
      floatx4 st0 = z4, st1 = z4;
#pragma unroll
      for (int kf = 0; kf < 2; ++kf) {
        half8 kb = *(const half8*)(kl + row * 64 + (((kf << 2) | quad) ^ (row & 7)) * 8);
        st0 = __builtin_amdgcn_mfma_f32_16x16x32_f16(kb, qf[0][kf], st0, 0, 0, 0);
        st1 = __builtin_amdgcn_mfma_f32_16x16x32_f16(kb, qf[1][kf], st1, 0, 0, 0);
      }
      {
        half4_t pk;
        pk.x = (half_t)__builtin_amdgcn_exp2f(st0[0]);
        pk.y = (half_t)__builtin_amdgcn_exp2f(st0[1]);
        pk.z = (half_t)__builtin_amdgcn_exp2f(st0[2]);
        pk.w = (half_t)__builtin_amdgcn_exp2f(st0[3]);
        pf[0][nt] = pk;
      }
      {
        half4_t pk;
        pk.x = (half_t)__builtin_amdgcn_exp2f(st1[0]);
        pk.y = (half_t)__builtin_amdgcn_exp2f(st1[1]);
        pk.z = (half_t)__builtin_amdgcn_exp2f(st1[2]);
        pk.w = (half_t)__builtin_amdgcn_exp2f(st1[3]);
        pf[1][nt] = pk;
      }
    }

    // O[q][d] += P@V; B-frag V[j=jt2*16+quad*4+i][d=dt*16+l15] from vT LDS.
    // Row sums ride along as one extra ones-B MFMA per jt2 (no LDS read).
#pragma unroll
    for (int jt2 = 0; jt2 < 4; ++jt2) {
#pragma unroll
      for (int dt = 0; dt < 4; ++dt) {
        int row = dt * 16 + l15;
        int ch = (jt2 * 2 + (quad >> 1)) ^ (l15 & 7);
        half4_t vb = *(const half4_t*)(vl + row * 64 + ch * 8 + (quad & 1) * 4);
        o[0][dt] = __builtin_amdgcn_mfma_f32_16x16x16f16(pf[0][jt2], vb, o[0][dt], 0, 0, 0);
        o[1][dt] = __builtin_amdgcn_mfma_f32_16x16x16f16(pf[1][jt2], vb, o[1][dt], 0, 0, 0);
      }
      osum[0] = __builtin_amdgcn_mfma_f32_16x16x16f16(pf[0][jt2], vone, osum[0], 0, 0, 0);
      osum[1] = __builtin_amdgcn_mfma_f32_16x16x16f16(pf[1][jt2], vone, osum[1], 0, 0, 0);
    }
    cur ^= 1;
  }

  // osum[mi][r] = psum for q-row q0w + mi*16 + quad*4 + r (replicated over l15)
  if (l15 == 0) {
#pragma unroll
    for (int mi = 0; mi < 2; ++mi)
#pragma unroll
      for (int r = 0; r < 4; ++r)
        psums[((size_t)(js * 32 + bh)) * SEQ + q0w + mi * 16 + quad * 4 + r] = osum[mi][r];
  }

  // unnormalized O -> fp16 partials
#pragma unroll
  for (int mi = 0; mi < 2; ++mi)
#pragma unroll
    for (int r = 0; r < 4; ++r) {
      int n = q0w + mi * 16 + quad * 4 + r;
      size_t base = ((size_t)(js * 32 + bh) * SEQ + n) * DH;
#pragma unroll
      for (int dt = 0; dt < 4; ++dt)
        opart[base + dt * 16 + l15] = (half_t)o[mi][dt][r];
    }
}

// combine: out = (O0+O1) * softmax(head_w)[h] / (ps0+ps1), write fp16 attn16
__global__ __launch_bounds__(256) void combine(const half_t* __restrict__ opart,
                                               const float* __restrict__ psums,
                                               const float* __restrict__ head_w,
                                               half_t* __restrict__ attn16) {
  int idx = blockIdx.x * blockDim.x + threadIdx.x;  // 1M threads, 4 d each
  int d4 = idx & 15, n = (idx >> 4) & 2047, bh = idx >> 15;
  int h = bh & 15, b = bh >> 4;
  const size_t jstr = (size_t)32 * SEQ * DH;
  size_t off = ((size_t)bh * SEQ + n) * DH + d4 * 4;
  half4_t o0 = *(const half4_t*)(opart + off);
  half4_t o1 = *(const half4_t*)(opart + jstr + off);
  float ps = psums[(size_t)bh * SEQ + n] + psums[(size_t)32 * SEQ + (size_t)bh * SEQ + n];

  float mw = head_w[0];
#pragma unroll
  for (int i = 1; i < NH; ++i) mw = fmaxf(mw, head_w[i]);
  float sw = 0.f;
#pragma unroll
  for (int i = 0; i < NH; ++i) sw += __expf(head_w[i] - mw);
  float hwv = __expf(head_w[h] - mw) / sw;

  float scl = hwv / ps;
  half4_t r;
  r.x = (half_t)(((float)o0.x + (float)o1.x) * scl);
  r.y = (half_t)(((float)o0.y + (float)o1.y) * scl);
  r.z = (half_t)(((float)o0.z + (float)o1.z) * scl);
  r.w = (half_t)(((float)o0.w + (float)o1.w) * scl);
  *(half4_t*)(attn16 + ((size_t)(b * SEQ + n)) * DIM_ + h * DH + d4 * 4) = r;
}

extern "C" void kernel_launch(void* const* d_in, const int* in_sizes, int n_in,
                              void* d_out, int out_size, void* d_ws, size_t ws_size,
                              hipStream_t stream) {
  const float* x = (const float*)d_in[0];
  const float* w_qkv = (const float*)d_in[1];
  const float* w_proj = (const float*)d_in[2];
  const float* head_w = (const float*)d_in[3];
  float* out = (float*)d_out;

  half_t* x16 = (half_t*)d_ws;                          // 4096*1024
  half_t* wq16 = x16 + (size_t)ROWS * DIM_;             // 3072*1024
  half_t* wp16 = wq16 + (size_t)3 * DIM_ * DIM_;        // 1024*1024
  half_t* q16 = wp16 + (size_t)DIM_ * DIM_;             // [B,H,N,Dh]
  half_t* k16 = q16 + (size_t)ROWS * DIM_;              // [B,H,N,Dh]
  half_t* vT16 = k16 + (size_t)ROWS * DIM_;             // [B,H,Dh,N]
  half_t* attn16 = vT16 + (size_t)ROWS * DIM_;          // [B*N, DIM]
  half_t* opart = attn16 + (size_t)ROWS * DIM_;         // [2][32][2048][64] fp16
  float* psums = (float*)(opart + (size_t)2 * 32 * SEQ * DH);  // [2][32][2048] f32

  const int nx = ROWS * DIM_ / 4, nq = 3 * DIM_ * DIM_ / 4, np = DIM_ * DIM_ / 4;
  convert_all<<<(nx + nq + np) / 256, 256, 0, stream>>>((const float4*)x, (const float4*)w_qkv,
                                                        (const float4*)w_proj, (half4_t*)x16,
                                                        nx, nq, np);

  gemm32<0, 128><<<dim3(24, 32), 256, 0, stream>>>(x16, wq16, q16, k16, vT16, nullptr);
  attn_p1<<<32 * 16 * 2, 256, 0, stream>>>(q16, k16, vT16, opart, psums);
  combine<<<(32 * SEQ * DH / 4) / 256, 256, 0, stream>>>(opart, psums, head_w, attn16);
  gemm32<1, 64><<<dim3(16, 32), 256, 0, stream>>>(attn16, wp16, nullptr, nullptr, nullptr, out);
}

// Round 10
// 193.501 us; speedup vs baseline: 1.0366x; 1.0366x over previous
//
#include <hip/hip_runtime.h>

typedef _Float16 half_t;
typedef _Float16 half8 __attribute__((ext_vector_type(8)));
typedef _Float16 half4_t __attribute__((ext_vector_type(4)));
typedef float floatx4 __attribute__((ext_vector_type(4)));
typedef float floatx16 __attribute__((ext_vector_type(16)));

#define B_SZ 2
#define SEQ 2048
#define DIM_ 1024
#define NH 16
#define DH 64
#define ROWS (B_SZ * SEQ)   // 4096

// async global->LDS, 16B per lane; LDS dest MUST be wave-uniform base (+lane*16)
__device__ __forceinline__ void gl2lds16(const void* g, void* l) {
  __builtin_amdgcn_global_load_lds((const __attribute__((address_space(1))) unsigned int*)g,
                                   (__attribute__((address_space(3))) unsigned int*)l, 16, 0, 0);
}

// one kernel converts x, w_qkv, w_proj (contiguous in ws) fp32->fp16
__global__ __launch_bounds__(256) void convert_all(const float4* __restrict__ x,
                                                   const float4* __restrict__ wq,
                                                   const float4* __restrict__ wp,
                                                   half4_t* __restrict__ dst,
                                                   int nx, int nq, int np) {
  int i = blockIdx.x * blockDim.x + threadIdx.x;
  float4 v;
  if (i < nx) v = x[i];
  else if (i < nx + nq) v = wq[i - nx];
  else if (i < nx + nq + np) v = wp[i - nx - nq];
  else return;
  half4_t h;
  h.x = (half_t)v.x; h.y = (half_t)v.y; h.z = (half_t)v.z; h.w = (half_t)v.w;
  dst[i] = h;
}

// C = A[4096][1024] @ Bt[N][1024]^T. 32x32x16 MFMA, BK=32, 128xBN tile, 4 waves.
// VGPR-staged pipeline: global_load -> regs (in flight ACROSS barriers; plain
// loads are thread-private so __syncthreads drains lgkm only, not vmcnt) ->
// ds_write -> single-buffer LDS. Ping-pong reg sets avoid WAR stalls.
// MODE 0 (BN=128): qkv epilogue. MODE 1 (BN=64): proj fp32 out.
template <int MODE, int BN>
__global__ __launch_bounds__(256, 3) void gemm32(const half_t* __restrict__ A,
                                                 const half_t* __restrict__ Bt,
                                                 half_t* __restrict__ q16,
                                                 half_t* __restrict__ k16,
                                                 half_t* __restrict__ vT16,
                                                 float* __restrict__ outp) {
  constexpr int K = 1024;
  constexpr int BK = 32;
  constexpr int NT = BN / 64;   // 32x32 n-tiles per wave
  constexpr int NB = BN / 64;   // B staging segs per thread
  __shared__ __align__(16) half_t a_lds[128 * BK];
  __shared__ __align__(16) half_t b_lds[BN * BK];
  const int t = threadIdx.x;
  const int wave = t >> 6, lane = t & 63;
  const int l31 = lane & 31, hw = lane >> 5;
  const int wm = wave >> 1, wn = wave & 1;
  const int row0 = blockIdx.y * 128, col0 = blockIdx.x * BN;

  // staging geometry: seg s -> row=s>>2, chunk c=s&3, swizzle sc=c^((row>>1)&3);
  // LDS pos = s*8 halfs. Thread t owns segs {t, t+256} for A, {t+hi*256} for B.
  int rowA[2], scA[2];
#pragma unroll
  for (int hi = 0; hi < 2; ++hi) {
    int s = t + hi * 256;
    rowA[hi] = s >> 2;
    scA[hi] = (s & 3) ^ ((rowA[hi] >> 1) & 3);
  }
  int rowB[NB], scB[NB];
#pragma unroll
  for (int hi = 0; hi < NB; ++hi) {
    int s = t + hi * 256;
    rowB[hi] = s >> 2;
    scB[hi] = (s & 3) ^ ((rowB[hi] >> 1) & 3);
  }

  floatx16 acc[2][NT];
#pragma unroll
  for (int i = 0; i < 2; ++i)
#pragma unroll
    for (int j = 0; j < NT; ++j)
#pragma unroll
      for (int r = 0; r < 16; ++r) acc[i][j][r] = 0.f;

  half8 sa[2][2], sb[2][NB];  // ping-pong staging regs

  auto loadT = [&](int pp, int k0) {
#pragma unroll
    for (int hi = 0; hi < 2; ++hi)
      sa[pp][hi] = *(const half8*)(A + (size_t)(row0 + rowA[hi]) * K + (k0 + scA[hi] * 8));
#pragma unroll
    for (int hi = 0; hi < NB; ++hi)
      sb[pp][hi] = *(const half8*)(Bt + (size_t)(col0 + rowB[hi]) * K + (k0 + scB[hi] * 8));
  };

  loadT(0, 0);
  int pp = 0;
  for (int k0 = 0; k0 < K; k0 += BK) {
    // publish staged regs to LDS (vmcnt wait attaches here, overlapped w/ prev compute)
#pragma unroll
    for (int hi = 0; hi < 2; ++hi)
      *(half8*)(&a_lds[(t + hi * 256) * 8]) = sa[pp][hi];
#pragma unroll
    for (int hi = 0; hi < NB; ++hi)
      *(half8*)(&b_lds[(t + hi * 256) * 8]) = sb[pp][hi];
    __syncthreads();  // lgkm drain only — plain global loads stay in flight

    if (k0 + BK < K) loadT(pp ^ 1, k0 + BK);  // prefetch next tile into other reg set

#pragma unroll
    for (int kf = 0; kf < 2; ++kf) {
      half8 af[2], bf[NT];
#pragma unroll
      for (int mt = 0; mt < 2; ++mt) {
        int row = wm * 64 + mt * 32 + l31;
        af[mt] = *(const half8*)(&a_lds[row * BK + (((kf << 1) | hw) ^ ((row >> 1) & 3)) * 8]);
      }
#pragma unroll
      for (int nt = 0; nt < NT; ++nt) {
        int row = wn * (BN / 2) + nt * 32 + l31;
        bf[nt] = *(const half8*)(&b_lds[row * BK + (((kf << 1) | hw) ^ ((row >> 1) & 3)) * 8]);
      }
#pragma unroll
      for (int mt = 0; mt < 2; ++mt)
#pragma unroll
        for (int nt = 0; nt < NT; ++nt)
          acc[mt][nt] = __builtin_amdgcn_mfma_f32_32x32x16_f16(af[mt], bf[nt], acc[mt][nt], 0, 0, 0);
    }
    __syncthreads();  // readers done before next ds_write
    pp ^= 1;
  }

  // C/D 32x32 mapping: col = lane&31, row = (r&3) + 8*(r>>2) + 4*(lane>>5)
  if (MODE == 0) {
    const int which = col0 >> 10;
#pragma unroll
    for (int mt = 0; mt < 2; ++mt)
#pragma unroll
      for (int nt = 0; nt < NT; ++nt) {
        int growb = row0 + wm * 64 + mt * 32;
        int gcol = col0 + wn * (BN / 2) + nt * 32 + l31;
        int hc = gcol & 1023, h = hc >> 6, d = hc & 63;
        if (which == 2) {
#pragma unroll
          for (int rq = 0; rq < 4; ++rq) {
            int grow = growb + 8 * rq + 4 * hw;
            int b = grow >> 11, n0 = grow & 2047;
            int bh = b * NH + h;
            half4_t h4;
            h4.x = (half_t)acc[mt][nt][rq * 4 + 0];
            h4.y = (half_t)acc[mt][nt][rq * 4 + 1];
            h4.z = (half_t)acc[mt][nt][rq * 4 + 2];
            h4.w = (half_t)acc[mt][nt][rq * 4 + 3];
            *(half4_t*)(vT16 + ((size_t)bh * DH + d) * SEQ + n0) = h4;
          }
        } else {
#pragma unroll
          for (int r = 0; r < 16; ++r) {
            int grow = growb + (r & 3) + 8 * (r >> 2) + 4 * hw;
            int b = grow >> 11, n = grow & 2047;
            int bh = b * NH + h;
            float v = acc[mt][nt][r];
            if (which == 0)
              // fold SCALE * log2(e): attn uses exp2
              q16[((size_t)bh * SEQ + n) * DH + d] = (half_t)(v * 0.18033688011112042f);
            else
              k16[((size_t)bh * SEQ + n) * DH + d] = (half_t)v;
          }
        }
      }
  } else {
#pragma unroll
    for (int mt = 0; mt < 2; ++mt)
#pragma unroll
      for (int nt = 0; nt < NT; ++nt) {
        int growb = row0 + wm * 64 + mt * 32;
        int gcol = col0 + wn * (BN / 2) + nt * 32 + l31;
#pragma unroll
        for (int r = 0; r < 16; ++r) {
          int grow = growb + (r & 3) + 8 * (r >> 2) + 4 * hw;
          outp[(size_t)grow * DIM_ + gcol] = acc[mt][nt][r];
        }
      }
  }
}

// Flash attention pass 1, j-split 2-way. Block = (bh, 128 q-rows, j-half).
// 4 waves x 32 q-rows (2 m-tiles), S^T trick (P^T regs feed K=16 PV MFMA).
// p = exp2(S') with log2e pre-folded into q. Row-sums via O_extra = P @ ones
// MFMA (register-aligned with o; no shuffles). launch_bounds(256,4).
__global__ __launch_bounds__(256, 4) void attn_p1(const half_t* __restrict__ q16,
                                                  const half_t* __restrict__ k16,
                                                  const half_t* __restrict__ vT16,
                                                  half_t* __restrict__ opart,
                                                  float* __restrict__ psums) {
  __shared__ __align__(16) half_t k_lds[2][64 * 64];  // [j][d]
  __shared__ __align__(16) half_t v_lds[2][64 * 64];  // vT: [d][j]

  const int t = threadIdx.x;
  const int wave = t >> 6, lane = t & 63;
  const int l15 = lane & 15, quad = lane >> 4;
  const int blk = blockIdx.x;
  const int js = blk & 1, qt = (blk >> 1) & 15, bh = blk >> 5;
  const half_t* qp = q16 + (size_t)bh * SEQ * DH;
  const half_t* kp = k16 + (size_t)bh * SEQ * DH;
  const half_t* vp = vT16 + (size_t)bh * DH * SEQ;
  const int q0w = qt * 128 + wave * 32;
  const int jbase = js * 1024;

  // staging offsets: 512 segs of 16B (64 rows x 8 chunks), chunk XOR row&7
  const int s0 = t, s1 = t + 256;
  const int r0_ = s0 >> 3, c0_ = (s0 & 7) ^ (r0_ & 7);
  const int r1_ = s1 >> 3, c1_ = (s1 & 7) ^ (r1_ & 7);

  // Q fragments, B-operand layout: lane l15 = q-row, k = kf*32 + quad*8 + i
  half8 qf[2][2];
#pragma unroll
  for (int mi = 0; mi < 2; ++mi)
#pragma unroll
    for (int kf = 0; kf < 2; ++kf)
      qf[mi][kf] = *(const half8*)(qp + (size_t)(q0w + mi * 16 + l15) * DH + kf * 32 + quad * 8);

  const floatx4 z4 = {0.f, 0.f, 0.f, 0.f};
  floatx4 o[2][4];   // [mi][d-tile], C/D: row=q(quad*4+r), col=d(l15)
  floatx4 osum[2];   // row-sums via P @ ones, same C/D layout (col-replicated)
#pragma unroll
  for (int mi = 0; mi < 2; ++mi) {
    osum[mi] = z4;
#pragma unroll
    for (int i = 0; i < 4; ++i) o[mi][i] = z4;
  }

  gl2lds16(kp + (size_t)(jbase + r0_) * DH + c0_ * 8, &k_lds[0][(wave * 64) * 8]);
  gl2lds16(vp + (size_t)r0_ * SEQ + jbase + c0_ * 8, &v_lds[0][(wave * 64) * 8]);
  gl2lds16(kp + (size_t)(jbase + r1_) * DH + c1_ * 8, &k_lds[0][(wave * 64 + 256) * 8]);
  gl2lds16(vp + (size_t)r1_ * SEQ + jbase + c1_ * 8, &v_lds[0][(wave * 64 + 256) * 8]);

  const half_t one_h = (half_t)1.f;
  const half4_t vone = {one_h, one_h, one_h, one_h};

  int cur = 0;
  for (int jt = 0; jt < 16; ++jt) {
    __syncthreads();  // publishes buf[cur], protects buf[cur^1]

    if (jt + 1 < 16) {
      const int j0 = jbase + (jt + 1) * 64, nb = cur ^ 1;
      gl2lds16(kp + (size_t)(j0 + r0_) * DH + c0_ * 8, &k_lds[nb][(wave * 64) * 8]);
      gl2lds16(vp + (size_t)r0_ * SEQ + j0 + c0_ * 8, &v_lds[nb][(wave * 64) * 8]);
      gl2lds16(kp + (size_t)(j0 + r1_) * DH + c1_ * 8, &k_lds[nb][(wave * 64 + 256) * 8]);
      gl2lds16(vp + (size_t)r1_ * SEQ + j0 + c1_ * 8, &v_lds[nb][(wave * 64 + 256) * 8]);
    }

    const half_t* kl = k_lds[cur];
    const half_t* vl = v_lds[cur];

    // Per nt: S^T MFMAs -> exp2 -> packed P fragment (st lives only 8 regs)
    half4_t pf[2][4];
#pragma unroll
    for (int nt = 0; nt < 4; ++nt) {
      int row = nt * 16 + l15;  // j-row
      floatx4 st0 = z4, st1 = z4;
#pragma unroll
      for (int kf = 0; kf < 2; ++kf) {
        half8 kb = *(const half8*)(kl + row * 64 + (((kf << 2) | quad) ^ (row & 7)) * 8);
        st0 = __builtin_amdgcn_mfma_f32_16x16x32_f16(kb, qf[0][kf], st0, 0, 0, 0);
        st1 = __builtin_amdgcn_mfma_f32_16x16x32_f16(kb, qf[1][kf], st1, 0, 0, 0);
      }
      {
        half4_t pk;
        pk.x = (half_t)__builtin_amdgcn_exp2f(st0[0]);
        pk.y = (half_t)__builtin_amdgcn_exp2f(st0[1]);
        pk.z = (half_t)__builtin_amdgcn_exp2f(st0[2]);
        pk.w = (half_t)__builtin_amdgcn_exp2f(st0[3]);
        pf[0][nt] = pk;
      }
      {
        half4_t pk;
        pk.x = (half_t)__builtin_amdgcn_exp2f(st1[0]);
        pk.y = (half_t)__builtin_amdgcn_exp2f(st1[1]);
        pk.z = (half_t)__builtin_amdgcn_exp2f(st1[2]);
        pk.w = (half_t)__builtin_amdgcn_exp2f(st1[3]);
        pf[1][nt] = pk;
      }
    }

    // O[q][d] += P@V; B-frag V[j=jt2*16+quad*4+i][d=dt*16+l15] from vT LDS.
    // Row sums ride along as one extra ones-B MFMA per jt2 (no LDS read).
#pragma unroll
    for (int jt2 = 0; jt2 < 4; ++jt2) {
#pragma unroll
      for (int dt = 0; dt < 4; ++dt) {
        int row = dt * 16 + l15;
        int ch = (jt2 * 2 + (quad >> 1)) ^ (l15 & 7);
        half4_t vb = *(const half4_t*)(vl + row * 64 + ch * 8 + (quad & 1) * 4);
        o[0][dt] = __builtin_amdgcn_mfma_f32_16x16x16f16(pf[0][jt2], vb, o[0][dt], 0, 0, 0);
        o[1][dt] = __builtin_amdgcn_mfma_f32_16x16x16f16(pf[1][jt2], vb, o[1][dt], 0, 0, 0);
      }
      osum[0] = __builtin_amdgcn_mfma_f32_16x16x16f16(pf[0][jt2], vone, osum[0], 0, 0, 0);
      osum[1] = __builtin_amdgcn_mfma_f32_16x16x16f16(pf[1][jt2], vone, osum[1], 0, 0, 0);
    }
    cur ^= 1;
  }

  // osum[mi][r] = psum for q-row q0w + mi*16 + quad*4 + r (replicated over l15)
  if (l15 == 0) {
#pragma unroll
    for (int mi = 0; mi < 2; ++mi)
#pragma unroll
      for (int r = 0; r < 4; ++r)
        psums[((size_t)(js * 32 + bh)) * SEQ + q0w + mi * 16 + quad * 4 + r] = osum[mi][r];
  }

  // unnormalized O -> fp16 partials
#pragma unroll
  for (int mi = 0; mi < 2; ++mi)
#pragma unroll
    for (int r = 0; r < 4; ++r) {
      int n = q0w + mi * 16 + quad * 4 + r;
      size_t base = ((size_t)(js * 32 + bh) * SEQ + n) * DH;
#pragma unroll
      for (int dt = 0; dt < 4; ++dt)
        opart[base + dt * 16 + l15] = (half_t)o[mi][dt][r];
    }
}

// combine: out = (O0+O1) * softmax(head_w)[h] / (ps0+ps1), write fp16 attn16
__global__ __launch_bounds__(256) void combine(const half_t* __restrict__ opart,
                                               const float* __restrict__ psums,
                                               const float* __restrict__ head_w,
                                               half_t* __restrict__ attn16) {
  int idx = blockIdx.x * blockDim.x + threadIdx.x;  // 1M threads, 4 d each
  int d4 = idx & 15, n = (idx >> 4) & 2047, bh = idx >> 15;
  int h = bh & 15, b = bh >> 4;
  const size_t jstr = (size_t)32 * SEQ * DH;
  size_t off = ((size_t)bh * SEQ + n) * DH + d4 * 4;
  half4_t o0 = *(const half4_t*)(opart + off);
  half4_t o1 = *(const half4_t*)(opart + jstr + off);
  float ps = psums[(size_t)bh * SEQ + n] + psums[(size_t)32 * SEQ + (size_t)bh * SEQ + n];

  float mw = head_w[0];
#pragma unroll
  for (int i = 1; i < NH; ++i) mw = fmaxf(mw, head_w[i]);
  float sw = 0.f;
#pragma unroll
  for (int i = 0; i < NH; ++i) sw += __expf(head_w[i] - mw);
  float hwv = __expf(head_w[h] - mw) / sw;

  float scl = hwv / ps;
  half4_t r;
  r.x = (half_t)(((float)o0.x + (float)o1.x) * scl);
  r.y = (half_t)(((float)o0.y + (float)o1.y) * scl);
  r.z = (half_t)(((float)o0.z + (float)o1.z) * scl);
  r.w = (half_t)(((float)o0.w + (float)o1.w) * scl);
  *(half4_t*)(attn16 + ((size_t)(b * SEQ + n)) * DIM_ + h * DH + d4 * 4) = r;
}

extern "C" void kernel_launch(void* const* d_in, const int* in_sizes, int n_in,
                              void* d_out, int out_size, void* d_ws, size_t ws_size,
                              hipStream_t stream) {
  const float* x = (const float*)d_in[0];
  const float* w_qkv = (const float*)d_in[1];
  const float* w_proj = (const float*)d_in[2];
  const float* head_w = (const float*)d_in[3];
  float* out = (float*)d_out;

  half_t* x16 = (half_t*)d_ws;                          // 4096*1024
  half_t* wq16 = x16 + (size_t)ROWS * DIM_;             // 3072*1024
  half_t* wp16 = wq16 + (size_t)3 * DIM_ * DIM_;        // 1024*1024
  half_t* q16 = wp16 + (size_t)DIM_ * DIM_;             // [B,H,N,Dh]
  half_t* k16 = q16 + (size_t)ROWS * DIM_;              // [B,H,N,Dh]
  half_t* vT16 = k16 + (size_t)ROWS * DIM_;             // [B,H,Dh,N]
  half_t* attn16 = vT16 + (size_t)ROWS * DIM_;          // [B*N, DIM]
  half_t* opart = attn16 + (size_t)ROWS * DIM_;         // [2][32][2048][64] fp16
  float* psums = (float*)(opart + (size_t)2 * 32 * SEQ * DH);  // [2][32][2048] f32

  const int nx = ROWS * DIM_ / 4, nq = 3 * DIM_ * DIM_ / 4, np = DIM_ * DIM_ / 4;
  convert_all<<<(nx + nq + np) / 256, 256, 0, stream>>>((const float4*)x, (const float4*)w_qkv,
                                                        (const float4*)w_proj, (half4_t*)x16,
                                                        nx, nq, np);

  gemm32<0, 128><<<dim3(24, 32), 256, 0, stream>>>(x16, wq16, q16, k16, vT16, nullptr);
  attn_p1<<<32 * 16 * 2, 256, 0, stream>>>(q16, k16, vT16, opart, psums);
  combine<<<(32 * SEQ * DH / 4) / 256, 256, 0, stream>>>(opart, psums, head_w, attn16);
  gemm32<1, 64><<<dim3(16, 32), 256, 0, stream>>>(attn16, wp16, nullptr, nullptr, nullptr, out);
}